// Round 9
// baseline (223.519 us; speedup 1.0000x reference)
//
#include <hip/hip_runtime.h>

// SupProtoConLoss on MI355X — round 20: R16 base + 5 blocks/CU + pair-row
// LDS (conflict-free) + fast fused finisher.
// League: R16 78.9us k_row (best loop); R19 fused 102.5 = 78.9 + ~24us
// finisher tail (64 ORDERED agent-atomic loads/thread). Supertile remap
// time-neutral (FETCH 96->41MB, no dt) => not BW-bound; reverted.
// Changes vs R16/R19:
//  (a) launch_bounds(256,5): 5x32KB = 160KB LDS exactly -> 20 waves/CU
//      (+25% TLP on a latency-bound loop). Falls back to 4 if no fit.
//  (b) pair-row LDS map: two 64B rows share a 128B line; phys unit u ->
//      {pr=u>>3, ps=u&7, sp=ps^(pr&7), row=2pr+(sp>>2), slot=sp&3}.
//      Read ps=(quad+4*(c16&1))^(c16>>1): 8 lanes per 4-bank group =
//      2/bank = conflict-free (4.26M conflict-cy -> ~0).
//  (c) finisher: ONE __threadfence (acquire at kernel end, harmless) then
//      plain float4 loads (pipelined) -> tail ~24us -> ~4us.

#define NROW 8192
#define DDIM 512
#define NCLS 100
#define TILE 128
#define BK 32
#define NKS 16     // DDIM / BK
#define NTRI 2080  // 64*65/2 triangle tiles

typedef float f32x4 __attribute__((ext_vector_type(4)));
typedef short s16x8 __attribute__((ext_vector_type(8)));

#define GLOBAL_AS __attribute__((address_space(1)))
#define LDS_AS __attribute__((address_space(3)))

__device__ __forceinline__ unsigned short f2bf(float x) {
  unsigned int u = __builtin_bit_cast(unsigned int, x);
  u += 0x7FFFu + ((u >> 16) & 1u);  // round-to-nearest-even
  return (unsigned short)(u >> 16);
}

// One wave per row: L2-norm, scale, cast to bf16. Also zeroes row_pos/row_neg
// and the done-counter — k_row only touches them afterwards.
__global__ void __launch_bounds__(256) k_prep(
    const float* __restrict__ reps, float* __restrict__ row_pos,
    unsigned short* __restrict__ Rb, unsigned* __restrict__ cnt) {
  const int wave = threadIdx.x >> 6;
  const int lane = threadIdx.x & 63;
  const int row = blockIdx.x * 4 + wave;
  if (threadIdx.x < 8) row_pos[blockIdx.x * 8 + threadIdx.x] = 0.0f;
  if (blockIdx.x == 0 && threadIdx.x == 0) cnt[0] = 0u;
  const float* r = reps + (size_t)row * DDIM;
  float4 v0 = *(const float4*)(r + lane * 4);
  float4 v1 = *(const float4*)(r + 256 + lane * 4);
  float ss = v0.x * v0.x + v0.y * v0.y + v0.z * v0.z + v0.w * v0.w +
             v1.x * v1.x + v1.y * v1.y + v1.z * v1.z + v1.w * v1.w;
#pragma unroll
  for (int m = 1; m < 64; m <<= 1) ss += __shfl_xor(ss, m);
  const float scale = 1.0f / sqrtf(ss);  // norms ~22.6; 1e-8 clamp unreachable
  ushort4 a, b;
  a.x = f2bf(v0.x * scale); a.y = f2bf(v0.y * scale);
  a.z = f2bf(v0.z * scale); a.w = f2bf(v0.w * scale);
  b.x = f2bf(v1.x * scale); b.y = f2bf(v1.y * scale);
  b.z = f2bf(v1.z * scale); b.w = f2bf(v1.w * scale);
  *(ushort4*)(Rb + (size_t)row * DDIM + lane * 4) = a;
  *(ushort4*)(Rb + (size_t)row * DDIM + 256 + lane * 4) = b;
}

// Block = one upper-triangle 128x128 tile (tm <= tn), sqrt decode (R16).
// 4 waves as 2M x 2N; wave tile 64x64 = acc[4][4] of 16x16x32.
// LDS per buf: A tile 4096 shorts | B tile 4096 shorts, pair-row layout.
__global__ void __launch_bounds__(256, 5) k_row(
    const unsigned short* __restrict__ Rb, const int* __restrict__ labels,
    float* __restrict__ row_pos, float* __restrict__ row_neg,
    unsigned* __restrict__ cnt, float* __restrict__ out) {
  const int t = blockIdx.x;
  int tn = (int)((sqrtf(8.0f * (float)t + 1.0f) - 1.0f) * 0.5f);
  while ((tn + 1) * (tn + 2) / 2 <= t) ++tn;
  while (tn * (tn + 1) / 2 > t) --tn;
  const int tm = t - tn * (tn + 1) / 2;  // 0..tn
  const int i0 = tm * TILE;
  const int j0 = tn * TILE;
  const bool diag = (tm == tn);

  __shared__ __attribute__((aligned(16))) unsigned short LDSH[2][2][TILE][BK];
  unsigned short* LF = &LDSH[0][0][0][0];

  const int tid = threadIdx.x;
  const int lane = tid & 63;
  const int wave = tid >> 6;  // 0..3
  const int wr = wave >> 1, wc = wave & 1;
  const int quad = lane >> 4, c16 = lane & 15;

  // ---- staging source (pair-row map): phys unit u -> logical (row, slot).
  unsigned sb[2][2];  // [mat][t] per-lane source base (shorts)
#pragma unroll
  for (int mt = 0; mt < 2; ++mt) {
    const int r0 = mt ? j0 : i0;
#pragma unroll
    for (int tt = 0; tt < 2; ++tt) {
      const unsigned u = wave * 128 + tt * 64 + lane;  // 16B unit in mat tile
      const unsigned pr = u >> 3, ps = u & 7;
      const unsigned sp = ps ^ (pr & 7);
      const unsigned row = pr * 2 + (sp >> 2);
      const unsigned slot = sp & 3;
      sb[mt][tt] = (unsigned)(r0 + row) * DDIM + slot * 8;
    }
  }

  auto stage = [&](int kt, int bb) {
    const int koff = kt * BK;
#pragma unroll
    for (int mt = 0; mt < 2; ++mt)
#pragma unroll
      for (int tt = 0; tt < 2; ++tt) {
        const unsigned short* src = Rb + sb[mt][tt] + koff;
        __builtin_amdgcn_global_load_lds(
            (GLOBAL_AS void*)const_cast<unsigned short*>(src),
            (LDS_AS void*)(LF + bb * 8192 + mt * 4096 +
                           (wave * 128 + tt * 64) * 8),
            16, 0, 0);
      }
  };

  // ---- frag read bases (pair-row map). row = wr*64 + m*16 + c16 ->
  // pr = wr*32 + m*8 + (c16>>1); pr&7 = c16>>1; ps = (quad+4*(c16&1))^(c16>>1)
  const int c16h = c16 >> 1;
  const int psr = (quad + 4 * (c16 & 1)) ^ c16h;
  const int aBase = wr * 2048 + c16h * 64 + psr * 8;
  const int bBase = 4096 + wc * 2048 + c16h * 64 + psr * 8;
  auto LD = [&](int si) { return *(const s16x8*)(LF + si); };

  f32x4 acc[4][4];
#pragma unroll
  for (int m = 0; m < 4; ++m)
#pragma unroll
    for (int n = 0; n < 4; ++n) acc[m][n] = (f32x4)0.0f;

  stage(0, 0);
  __syncthreads();

#pragma unroll 2
  for (int kt = 0; kt < NKS; ++kt) {
    const int cur = kt & 1;
    if (kt < NKS - 1) stage(kt + 1, cur ^ 1);  // early issue, ~full iter to land
    const int cb = cur * 8192;
    s16x8 af[4], bf[4];
#pragma unroll
    for (int m = 0; m < 4; ++m) af[m] = LD(cb + aBase + m * 512);
#pragma unroll
    for (int n = 0; n < 4; ++n) bf[n] = LD(cb + bBase + n * 512);
#pragma unroll
    for (int m = 0; m < 4; ++m)
#pragma unroll
      for (int n = 0; n < 4; ++n)
        acc[m][n] = __builtin_amdgcn_mfma_f32_16x16x32_bf16(af[m], bf[n],
                                                            acc[m][n], 0, 0, 0);
    __syncthreads();  // drains stage(kt+1) DMAs + buffer-swap hazard
  }

  // ---- Epilogue: fold tile into row-i sums and (off-diag) row-j sums.
  float* rp = (float*)(void*)LF;  // 128 rpos | 128 rneg | 128 cpos | 128 cneg
  float* rn = rp + 128;
  float* cp = rn + 128;
  float* cn = cp + 128;
  rp[tid] = 0.0f;
  rp[tid + 256] = 0.0f;
  __syncthreads();

  const float C0 = -5.0f + 1e-7f;  // s = 5g - 5 + 1e-7 (static shift S=10)
  int lj4[4], gj4[4];
#pragma unroll
  for (int n = 0; n < 4; ++n) {
    gj4[n] = j0 + wc * 64 + n * 16 + c16;
    lj4[n] = labels[gj4[n]];
  }
  float psj[4] = {0.0f, 0.0f, 0.0f, 0.0f};
  float nsj[4] = {0.0f, 0.0f, 0.0f, 0.0f};
#pragma unroll
  for (int m = 0; m < 4; ++m) {
#pragma unroll
    for (int r = 0; r < 4; ++r) {
      const int lrow = wr * 64 + m * 16 + quad * 4 + r;
      const int gi = i0 + lrow;
      const int li = labels[gi];
      float psi = 0.0f, nsi = 0.0f;
#pragma unroll
      for (int n = 0; n < 4; ++n) {
        const float g2 = acc[m][n][r];
        const float sv = fmaf(g2, 5.0f, C0);
        const float ev = __expf(sv);
        const bool same = (li == lj4[n]);
        const bool ok = same && (gi != gj4[n]);
        psi += ok ? sv : 0.0f;
        nsi += same ? 0.0f : ev;
        psj[n] += ok ? sv : 0.0f;  // col-side accumulation (over m,r)
        nsj[n] += same ? 0.0f : ev;
      }
#pragma unroll
      for (int s = 1; s < 16; s <<= 1) {  // reduce over the 16 c16 lanes
        psi += __shfl_xor(psi, s);
        nsi += __shfl_xor(nsi, s);
      }
      if (c16 == 0) {
        atomicAdd(&rp[lrow], psi);
        atomicAdd(&rn[lrow], nsi);
      }
    }
  }
  if (!diag) {  // col-side: reduce over quad groups, cross-wr via LDS atomics
#pragma unroll
    for (int n = 0; n < 4; ++n) {
      float p = psj[n], q = nsj[n];
      p += __shfl_xor(p, 16); p += __shfl_xor(p, 32);
      q += __shfl_xor(q, 16); q += __shfl_xor(q, 32);
      if (quad == 0) {
        atomicAdd(&cp[wc * 64 + n * 16 + c16], p);
        atomicAdd(&cn[wc * 64 + n * 16 + c16], q);
      }
    }
  }
  __syncthreads();
  if (tid < 128) {
    atomicAdd(&row_pos[i0 + tid], rp[tid]);
    atomicAdd(&row_neg[i0 + tid], rn[tid]);
  } else if (!diag) {
    atomicAdd(&row_pos[j0 + tid - 128], cp[tid - 128]);
    atomicAdd(&row_neg[j0 + tid - 128], cn[tid - 128]);
  }
  __syncthreads();  // vmcnt(0): all this block's device-scope RMWs acked

  // ---- last-block-done finisher (fused k_final).
  unsigned* flg = (unsigned*)(void*)LF + 600;  // outside the [0,512) floats
  if (tid == 0) flg[0] = atomicAdd(cnt, 1u);
  __syncthreads();
  if (flg[0] != NTRI - 1) return;

  // ONE acquire-style fence (inv stale lines) -> plain pipelined loads are
  // then coherent with the producers' coherence-point RMWs. R18's mistake
  // was 2080 of these mid-flight; a single one at kernel end is free.
  __threadfence();

  int* hcnt = (int*)(void*)LF;  // reuse LDS: 100 ints
  float* fs = (float*)(void*)LF + 128;
  float* fc = fs + 8;
  if (tid < NCLS) hcnt[tid] = 0;
  __syncthreads();
  for (int i = tid; i < NROW; i += 256) atomicAdd(&hcnt[labels[i]], 1);
  __syncthreads();
  float lsum = 0.0f, lcnt = 0.0f;
  const float4* rp4 = (const float4*)row_pos;
  const float4* rn4 = (const float4*)row_neg;
#pragma unroll 2
  for (int i = tid; i < NROW / 4; i += 256) {
    const float4 p4 = rp4[i];
    const float4 n4 = rn4[i];
    const float pv[4] = {p4.x, p4.y, p4.z, p4.w};
    const float nv[4] = {n4.x, n4.y, n4.z, n4.w};
#pragma unroll
    for (int e = 0; e < 4; ++e) {
      const int row = i * 4 + e;
      const float c = (float)(hcnt[labels[row]] - 1);
      const float pos = pv[e] / (c + 1e-8f);
      const float loss = -pos + logf(nv[e] + 1e-8f);
      if (loss > 0.0f) { lsum += loss; lcnt += 1.0f; }
    }
  }
#pragma unroll
  for (int m = 1; m < 64; m <<= 1) {
    lsum += __shfl_xor(lsum, m);
    lcnt += __shfl_xor(lcnt, m);
  }
  if (lane == 0) { fs[wave] = lsum; fc[wave] = lcnt; }
  __syncthreads();
  if (tid == 0) {
    float S = 0.0f, C = 0.0f;
#pragma unroll
    for (int w = 0; w < 4; ++w) { S += fs[w]; C += fc[w]; }
    out[0] = S / (C + 1e-8f);
  }
}

extern "C" void kernel_launch(void* const* d_in, const int* in_sizes, int n_in,
                              void* d_out, int out_size, void* d_ws, size_t ws_size,
                              hipStream_t stream) {
  const float* reps = (const float*)d_in[0];
  const int* labels = (const int*)d_in[1];
  float* out = (float*)d_out;
  char* ws = (char*)d_ws;
  // ws layout: Rb (bf16 normalized reps, 8 MiB) | row_pos | row_neg | cnt
  unsigned short* Rb = (unsigned short*)ws;
  float* row_pos = (float*)(ws + (size_t)NROW * DDIM * 2);
  float* row_neg = row_pos + NROW;
  unsigned* cnt = (unsigned*)(row_neg + NROW);

  k_prep<<<NROW / 4, 256, 0, stream>>>(reps, row_pos, Rb, cnt);
  k_row<<<NTRI, 256, 0, stream>>>(Rb, labels, row_pos, row_neg, cnt, out);
  (void)in_sizes; (void)n_in; (void)out_size; (void)ws_size;
}

// Round 10
// 151.322 us; speedup vs baseline: 1.4771x; 1.4771x over previous
//
#include <hip/hip_runtime.h>

// SupProtoConLoss on MI355X — round 21: R20 with launch_bounds back to 4.
// League: R16 78.9 k_row / 147.5 total; R19 fused 102.5 (finisher tail
// ~24us of ORDERED agent-atomic loads); R20 REGRESSED to ~170us k_row:
// launch_bounds(256,5) forced VGPR 64->48 => in-loop scratch spill (WRITE
// 45->227MB, FETCH 185MB) with NO occupancy gain (34.8 == R16's 35).
// R20's verified wins kept: pair-row LDS map (conflicts 4.26M -> 1058) and
// fast finisher (one fence + pipelined float4 loads). R21 = R20 but
// __launch_bounds__(256,4): restore R16's register allocation, no spill.

#define NROW 8192
#define DDIM 512
#define NCLS 100
#define TILE 128
#define BK 32
#define NKS 16     // DDIM / BK
#define NTRI 2080  // 64*65/2 triangle tiles

typedef float f32x4 __attribute__((ext_vector_type(4)));
typedef short s16x8 __attribute__((ext_vector_type(8)));

#define GLOBAL_AS __attribute__((address_space(1)))
#define LDS_AS __attribute__((address_space(3)))

__device__ __forceinline__ unsigned short f2bf(float x) {
  unsigned int u = __builtin_bit_cast(unsigned int, x);
  u += 0x7FFFu + ((u >> 16) & 1u);  // round-to-nearest-even
  return (unsigned short)(u >> 16);
}

// One wave per row: L2-norm, scale, cast to bf16. Also zeroes row_pos/row_neg
// and the done-counter — k_row only touches them afterwards.
__global__ void __launch_bounds__(256) k_prep(
    const float* __restrict__ reps, float* __restrict__ row_pos,
    unsigned short* __restrict__ Rb, unsigned* __restrict__ cnt) {
  const int wave = threadIdx.x >> 6;
  const int lane = threadIdx.x & 63;
  const int row = blockIdx.x * 4 + wave;
  if (threadIdx.x < 8) row_pos[blockIdx.x * 8 + threadIdx.x] = 0.0f;
  if (blockIdx.x == 0 && threadIdx.x == 0) cnt[0] = 0u;
  const float* r = reps + (size_t)row * DDIM;
  float4 v0 = *(const float4*)(r + lane * 4);
  float4 v1 = *(const float4*)(r + 256 + lane * 4);
  float ss = v0.x * v0.x + v0.y * v0.y + v0.z * v0.z + v0.w * v0.w +
             v1.x * v1.x + v1.y * v1.y + v1.z * v1.z + v1.w * v1.w;
#pragma unroll
  for (int m = 1; m < 64; m <<= 1) ss += __shfl_xor(ss, m);
  const float scale = 1.0f / sqrtf(ss);  // norms ~22.6; 1e-8 clamp unreachable
  ushort4 a, b;
  a.x = f2bf(v0.x * scale); a.y = f2bf(v0.y * scale);
  a.z = f2bf(v0.z * scale); a.w = f2bf(v0.w * scale);
  b.x = f2bf(v1.x * scale); b.y = f2bf(v1.y * scale);
  b.z = f2bf(v1.z * scale); b.w = f2bf(v1.w * scale);
  *(ushort4*)(Rb + (size_t)row * DDIM + lane * 4) = a;
  *(ushort4*)(Rb + (size_t)row * DDIM + 256 + lane * 4) = b;
}

// Block = one upper-triangle 128x128 tile (tm <= tn), sqrt decode (R16).
// 4 waves as 2M x 2N; wave tile 64x64 = acc[4][4] of 16x16x32.
// LDS per buf: A tile 4096 shorts | B tile 4096 shorts, pair-row layout:
// two 64B rows share a 128B line; phys 16B-unit u -> {pr=u>>3, ps=u&7,
// sp=ps^(pr&7), row=2pr+(sp>>2), slot=sp&3}. Conflict-free on read
// (ps=(quad+4*(c16&1))^(c16>>1): 2 lanes/bank) — verified: 4.26M -> 1058.
__global__ void __launch_bounds__(256, 4) k_row(
    const unsigned short* __restrict__ Rb, const int* __restrict__ labels,
    float* __restrict__ row_pos, float* __restrict__ row_neg,
    unsigned* __restrict__ cnt, float* __restrict__ out) {
  const int t = blockIdx.x;
  int tn = (int)((sqrtf(8.0f * (float)t + 1.0f) - 1.0f) * 0.5f);
  while ((tn + 1) * (tn + 2) / 2 <= t) ++tn;
  while (tn * (tn + 1) / 2 > t) --tn;
  const int tm = t - tn * (tn + 1) / 2;  // 0..tn
  const int i0 = tm * TILE;
  const int j0 = tn * TILE;
  const bool diag = (tm == tn);

  __shared__ __attribute__((aligned(16))) unsigned short LDSH[2][2][TILE][BK];
  unsigned short* LF = &LDSH[0][0][0][0];

  const int tid = threadIdx.x;
  const int lane = tid & 63;
  const int wave = tid >> 6;  // 0..3
  const int wr = wave >> 1, wc = wave & 1;
  const int quad = lane >> 4, c16 = lane & 15;

  // ---- staging source (pair-row map): phys unit u -> logical (row, slot).
  unsigned sb[2][2];  // [mat][t] per-lane source base (shorts)
#pragma unroll
  for (int mt = 0; mt < 2; ++mt) {
    const int r0 = mt ? j0 : i0;
#pragma unroll
    for (int tt = 0; tt < 2; ++tt) {
      const unsigned u = wave * 128 + tt * 64 + lane;  // 16B unit in mat tile
      const unsigned pr = u >> 3, ps = u & 7;
      const unsigned sp = ps ^ (pr & 7);
      const unsigned row = pr * 2 + (sp >> 2);
      const unsigned slot = sp & 3;
      sb[mt][tt] = (unsigned)(r0 + row) * DDIM + slot * 8;
    }
  }

  auto stage = [&](int kt, int bb) {
    const int koff = kt * BK;
#pragma unroll
    for (int mt = 0; mt < 2; ++mt)
#pragma unroll
      for (int tt = 0; tt < 2; ++tt) {
        const unsigned short* src = Rb + sb[mt][tt] + koff;
        __builtin_amdgcn_global_load_lds(
            (GLOBAL_AS void*)const_cast<unsigned short*>(src),
            (LDS_AS void*)(LF + bb * 8192 + mt * 4096 +
                           (wave * 128 + tt * 64) * 8),
            16, 0, 0);
      }
  };

  // ---- frag read bases (pair-row map). row = wr*64 + m*16 + c16 ->
  // pr = wr*32 + m*8 + (c16>>1); pr&7 = c16>>1; ps = (quad+4*(c16&1))^(c16>>1)
  const int c16h = c16 >> 1;
  const int psr = (quad + 4 * (c16 & 1)) ^ c16h;
  const int aBase = wr * 2048 + c16h * 64 + psr * 8;
  const int bBase = 4096 + wc * 2048 + c16h * 64 + psr * 8;
  auto LD = [&](int si) { return *(const s16x8*)(LF + si); };

  f32x4 acc[4][4];
#pragma unroll
  for (int m = 0; m < 4; ++m)
#pragma unroll
    for (int n = 0; n < 4; ++n) acc[m][n] = (f32x4)0.0f;

  stage(0, 0);
  __syncthreads();

#pragma unroll 2
  for (int kt = 0; kt < NKS; ++kt) {
    const int cur = kt & 1;
    if (kt < NKS - 1) stage(kt + 1, cur ^ 1);  // early issue, ~full iter to land
    const int cb = cur * 8192;
    s16x8 af[4], bf[4];
#pragma unroll
    for (int m = 0; m < 4; ++m) af[m] = LD(cb + aBase + m * 512);
#pragma unroll
    for (int n = 0; n < 4; ++n) bf[n] = LD(cb + bBase + n * 512);
#pragma unroll
    for (int m = 0; m < 4; ++m)
#pragma unroll
      for (int n = 0; n < 4; ++n)
        acc[m][n] = __builtin_amdgcn_mfma_f32_16x16x32_bf16(af[m], bf[n],
                                                            acc[m][n], 0, 0, 0);
    __syncthreads();  // drains stage(kt+1) DMAs + buffer-swap hazard
  }

  // ---- Epilogue: fold tile into row-i sums and (off-diag) row-j sums.
  float* rp = (float*)(void*)LF;  // 128 rpos | 128 rneg | 128 cpos | 128 cneg
  float* rn = rp + 128;
  float* cp = rn + 128;
  float* cn = cp + 128;
  rp[tid] = 0.0f;
  rp[tid + 256] = 0.0f;
  __syncthreads();

  const float C0 = -5.0f + 1e-7f;  // s = 5g - 5 + 1e-7 (static shift S=10)
  int lj4[4], gj4[4];
#pragma unroll
  for (int n = 0; n < 4; ++n) {
    gj4[n] = j0 + wc * 64 + n * 16 + c16;
    lj4[n] = labels[gj4[n]];
  }
  float psj[4] = {0.0f, 0.0f, 0.0f, 0.0f};
  float nsj[4] = {0.0f, 0.0f, 0.0f, 0.0f};
#pragma unroll
  for (int m = 0; m < 4; ++m) {
#pragma unroll
    for (int r = 0; r < 4; ++r) {
      const int lrow = wr * 64 + m * 16 + quad * 4 + r;
      const int gi = i0 + lrow;
      const int li = labels[gi];
      float psi = 0.0f, nsi = 0.0f;
#pragma unroll
      for (int n = 0; n < 4; ++n) {
        const float g2 = acc[m][n][r];
        const float sv = fmaf(g2, 5.0f, C0);
        const float ev = __expf(sv);
        const bool same = (li == lj4[n]);
        const bool ok = same && (gi != gj4[n]);
        psi += ok ? sv : 0.0f;
        nsi += same ? 0.0f : ev;
        psj[n] += ok ? sv : 0.0f;  // col-side accumulation (over m,r)
        nsj[n] += same ? 0.0f : ev;
      }
#pragma unroll
      for (int s = 1; s < 16; s <<= 1) {  // reduce over the 16 c16 lanes
        psi += __shfl_xor(psi, s);
        nsi += __shfl_xor(nsi, s);
      }
      if (c16 == 0) {
        atomicAdd(&rp[lrow], psi);
        atomicAdd(&rn[lrow], nsi);
      }
    }
  }
  if (!diag) {  // col-side: reduce over quad groups, cross-wr via LDS atomics
#pragma unroll
    for (int n = 0; n < 4; ++n) {
      float p = psj[n], q = nsj[n];
      p += __shfl_xor(p, 16); p += __shfl_xor(p, 32);
      q += __shfl_xor(q, 16); q += __shfl_xor(q, 32);
      if (quad == 0) {
        atomicAdd(&cp[wc * 64 + n * 16 + c16], p);
        atomicAdd(&cn[wc * 64 + n * 16 + c16], q);
      }
    }
  }
  __syncthreads();
  if (tid < 128) {
    atomicAdd(&row_pos[i0 + tid], rp[tid]);
    atomicAdd(&row_neg[i0 + tid], rn[tid]);
  } else if (!diag) {
    atomicAdd(&row_pos[j0 + tid - 128], cp[tid - 128]);
    atomicAdd(&row_neg[j0 + tid - 128], cn[tid - 128]);
  }
  __syncthreads();  // vmcnt(0): all this block's device-scope RMWs acked

  // ---- last-block-done finisher (fused k_final).
  unsigned* flg = (unsigned*)(void*)LF + 600;  // outside the [0,512) floats
  if (tid == 0) flg[0] = atomicAdd(cnt, 1u);
  __syncthreads();
  if (flg[0] != NTRI - 1) return;

  // ONE acquire-style fence (inv stale lines) -> plain pipelined loads are
  // then coherent with the producers' coherence-point RMWs. (R18's mistake
  // was 2080 of these mid-flight; a single one at kernel end is free.)
  __threadfence();

  int* hcnt = (int*)(void*)LF;  // reuse LDS: 100 ints
  float* fs = (float*)(void*)LF + 128;
  float* fc = fs + 8;
  if (tid < NCLS) hcnt[tid] = 0;
  __syncthreads();
  for (int i = tid; i < NROW; i += 256) atomicAdd(&hcnt[labels[i]], 1);
  __syncthreads();
  float lsum = 0.0f, lcnt = 0.0f;
  const float4* rp4 = (const float4*)row_pos;
  const float4* rn4 = (const float4*)row_neg;
#pragma unroll 2
  for (int i = tid; i < NROW / 4; i += 256) {
    const float4 p4 = rp4[i];
    const float4 n4 = rn4[i];
    const float pv[4] = {p4.x, p4.y, p4.z, p4.w};
    const float nv[4] = {n4.x, n4.y, n4.z, n4.w};
#pragma unroll
    for (int e = 0; e < 4; ++e) {
      const int row = i * 4 + e;
      const float c = (float)(hcnt[labels[row]] - 1);
      const float pos = pv[e] / (c + 1e-8f);
      const float loss = -pos + logf(nv[e] + 1e-8f);
      if (loss > 0.0f) { lsum += loss; lcnt += 1.0f; }
    }
  }
#pragma unroll
  for (int m = 1; m < 64; m <<= 1) {
    lsum += __shfl_xor(lsum, m);
    lcnt += __shfl_xor(lcnt, m);
  }
  if (lane == 0) { fs[wave] = lsum; fc[wave] = lcnt; }
  __syncthreads();
  if (tid == 0) {
    float S = 0.0f, C = 0.0f;
#pragma unroll
    for (int w = 0; w < 4; ++w) { S += fs[w]; C += fc[w]; }
    out[0] = S / (C + 1e-8f);
  }
}

extern "C" void kernel_launch(void* const* d_in, const int* in_sizes, int n_in,
                              void* d_out, int out_size, void* d_ws, size_t ws_size,
                              hipStream_t stream) {
  const float* reps = (const float*)d_in[0];
  const int* labels = (const int*)d_in[1];
  float* out = (float*)d_out;
  char* ws = (char*)d_ws;
  // ws layout: Rb (bf16 normalized reps, 8 MiB) | row_pos | row_neg | cnt
  unsigned short* Rb = (unsigned short*)ws;
  float* row_pos = (float*)(ws + (size_t)NROW * DDIM * 2);
  float* row_neg = row_pos + NROW;
  unsigned* cnt = (unsigned*)(row_neg + NROW);

  k_prep<<<NROW / 4, 256, 0, stream>>>(reps, row_pos, Rb, cnt);
  k_row<<<NTRI, 256, 0, stream>>>(Rb, labels, row_pos, row_neg, cnt, out);
  (void)in_sizes; (void)n_in; (void)out_size; (void)ws_size;
}